// Round 16
// baseline (111.034 us; speedup 1.0000x reference)
//
#include <hip/hip_runtime.h>

#define LNUM 12
#define TNUM 12
#define NPASS 7   // 1 initial pass + HORIZON=6

// ---------------------------------------------------------------------------
// Prep kernel (validated r7/r11): pre-scale weights/biases once into d_ws.
// ws layout, [group*12 + layer], groups:
//   0: wi0' = -log2e*w_ih[l][0]   1: wi1' = -log2e*w_ih[l][1]
//   2: wi2' =  2log2e*w_ih[l][2]  3: wh0' = -log2e*w_hh[l][0]
//   4: wh1' = -log2e*w_hh[l][1]   5: wh2' =  2log2e*w_hh[l][2]
//   6: b0'  = -log2e*(b_ih0+b_hh0) 7: b1' = -log2e*(b_ih1+b_hh1)
//   8: bi2' =  2log2e*b_ih[l][2]  9: bh2' = 2log2e*b_hh[l][2]
// ---------------------------------------------------------------------------
__global__ void gru_prep_kernel(const float* __restrict__ w_ih,
                                const float* __restrict__ w_hh,
                                const float* __restrict__ b_ih,
                                const float* __restrict__ b_hh,
                                float* __restrict__ ws) {
    const float NL2E = -1.4426950408889634f;
    const float TL2E =  2.8853900817779268f;
    int j = threadIdx.x;
    if (j >= 10 * LNUM) return;
    int g = j / LNUM, l = j % LNUM;
    float v;
    switch (g) {
        case 0: v = NL2E * w_ih[3*l+0]; break;
        case 1: v = NL2E * w_ih[3*l+1]; break;
        case 2: v = TL2E * w_ih[3*l+2]; break;
        case 3: v = NL2E * w_hh[3*l+0]; break;
        case 4: v = NL2E * w_hh[3*l+1]; break;
        case 5: v = TL2E * w_hh[3*l+2]; break;
        case 6: v = NL2E * (b_ih[3*l+0] + b_hh[3*l+0]); break;
        case 7: v = NL2E * (b_ih[3*l+1] + b_hh[3*l+1]); break;
        case 8: v = TL2E * b_ih[3*l+2]; break;
        default: v = TL2E * b_hh[3*l+2]; break;
    }
    ws[j] = v;
}

// One GRU cell for layer l (compile-time). Residency split (r7/r10/r11
// lessons): the 6 weights read straight from ws with uniform compile-time
// addresses -> compiler s_loads to SGPRs (LICM'd; r7 proved this path);
// the 4 biases come from the VGPR-pinned array B -> every v_fma has
// exactly ONE SGPR operand: no v_mov fixups, no spills.
// 14 VALU + 5 trans (shared-rcp double sigmoid, validated r7/r11).
__device__ __forceinline__ float cell(const float* __restrict__ ws,
                                      const float (&B)[4][LNUM],
                                      float (&h)[LNUM], const int l, float inp) {
    float ar = fmaf(inp,  ws[ 0 + l], fmaf(h[l], ws[36 + l], B[0][l]));
    float az = fmaf(inp,  ws[12 + l], fmaf(h[l], ws[48 + l], B[1][l]));
    float gn = fmaf(inp,  ws[24 + l], B[2][l]);
    float hg = fmaf(h[l], ws[60 + l], B[3][l]);

    float er = __builtin_amdgcn_exp2f(ar);
    float ez = __builtin_amdgcn_exp2f(az);
    float ea = 1.0f + er;
    float eb = 1.0f + ez;
    float D  = __builtin_amdgcn_rcpf(ea * eb);   // one rcp -> both sigmoids
    float r  = D * eb;
    float z  = D * ea;

    float en = __builtin_amdgcn_exp2f(fmaf(r, hg, gn));
    float u  = __builtin_amdgcn_rcpf(1.0f + en);
    float n  = fmaf(-2.0f, u, 1.0f);             // tanh

    float hn = fmaf(z, h[l], fmaf(-z, n, n));    // (1-z)n + z*h
    h[l] = hn;
    return hn;
}

// ---------------------------------------------------------------------------
// Diagonal-wavefront kernel (schedule validated r11, absmax 0.0): one thread
// per chain; cell (p,t,l) executed at diagonal d = 12p + t + l. Steady state
// = 12 independent cells per diagonal (12-way intra-thread ILP; no LDS, no
// barriers). In-place on h[12], descending l reads pre-diagonal values.
// Slot 0 input: seq[d] while d<12 (p==0), else pre-diagonal h[11].
// ---------------------------------------------------------------------------
__global__ __launch_bounds__(256, 1)
void gru_diag_kernel(const float* __restrict__ x,
                     const float* __restrict__ ws,
                     float* __restrict__ out,
                     int total) {
    const int tid = blockIdx.x * blockDim.x + threadIdx.x;
    if (tid >= total) return;

    // 48 biases pinned to VGPRs (asm blocks SGPR rematerialization -> avoids
    // r7's double-SGPR-operand v_movs). Weights deliberately NOT pinned:
    // 72 of them live happily in SGPRs (s_load); pinning all 120 to VGPRs
    // was r11's spill-to-scratch failure.
    float B[4][LNUM];
#pragma unroll
    for (int g = 0; g < 4; ++g) {
#pragma unroll
        for (int l = 0; l < LNUM; ++l) {
            float b = ws[72 + g * LNUM + l];
            asm volatile("" : "+v"(b));
            B[g][l] = b;
        }
    }

    // This chain's 12 inputs (contiguous 48B -> 3x float4).
    float seq[TNUM];
    const float4* xv = reinterpret_cast<const float4*>(x + (size_t)tid * TNUM);
#pragma unroll
    for (int i = 0; i < TNUM / 4; ++i) {
        float4 v = xv[i];
        seq[i*4+0] = v.x; seq[i*4+1] = v.y; seq[i*4+2] = v.z; seq[i*4+3] = v.w;
    }

    float h[LNUM];
#pragma unroll
    for (int l = 0; l < LNUM; ++l) h[l] = 0.0f;

    // ---- Prologue: d = 0..11 (slot l active iff l <= d; slot 0 reads seq[d]).
#pragma unroll
    for (int d = 0; d < 12; ++d) {
#pragma unroll
        for (int l = 11; l >= 1; --l) {
            if (l <= d) h[l] = cell(ws, B, h, l, h[l - 1]);
        }
        h[0] = cell(ws, B, h, 0, seq[d]);
    }

    // ---- Main: d = 12..83, all 12 slots active. top = pre-diagonal h[11]
    // = prev-pass top output at the slot-0 cell's time index (made at d-1).
#pragma unroll 1
    for (int d = 12; d < 84; ++d) {
        float top = h[11];
#pragma unroll
        for (int l = 11; l >= 1; --l) {
            h[l] = cell(ws, B, h, l, h[l - 1]);
        }
        h[0] = cell(ws, B, h, 0, top);
    }

    // ---- Epilogue: d = 84..94 (slot l active iff l >= d-83; slot 0 done).
#pragma unroll
    for (int d = 84; d < 95; ++d) {
#pragma unroll
        for (int l = 11; l >= 1; --l) {
            if (l >= d - 83) h[l] = cell(ws, B, h, l, h[l - 1]);
        }
    }

    // h[l] = final hidden state of layer l (cell (6,11,l)).
#pragma unroll
    for (int l = 0; l < LNUM; ++l) {
        out[(size_t)l * total + tid] = h[l];
    }
}

extern "C" void kernel_launch(void* const* d_in, const int* in_sizes, int n_in,
                              void* d_out, int out_size, void* d_ws, size_t ws_size,
                              hipStream_t stream) {
    const float* x    = (const float*)d_in[0];
    const float* w_ih = (const float*)d_in[1];
    const float* w_hh = (const float*)d_in[2];
    const float* b_ih = (const float*)d_in[3];
    const float* b_hh = (const float*)d_in[4];
    float* out = (float*)d_out;
    float* ws  = (float*)d_ws;

    gru_prep_kernel<<<1, 128, 0, stream>>>(w_ih, w_hh, b_ih, b_hh, ws);

    const int total = in_sizes[0] / TNUM;   // B*N = 65536 chains
    const int block = 256;
    const int grid  = (total + block - 1) / block;
    gru_diag_kernel<<<grid, block, 0, stream>>>(x, ws, out, total);
}